// Round 1
// baseline (74.286 us; speedup 1.0000x reference)
//
#include <hip/hip_runtime.h>

// Problem: BS=64, K=4, PTS=5, RES=28, STEPS=500. All tensors f32.
// Output (64,1,28,28) f32.
//
// Round-5 lesson: fused flag-sync version REGRESSED (85 vs 78 us) — agent
// scope release/acquire = whole-L2 writeback/invalidate storms on CDNA4.
// Round-6: t-subsampling stride 2 (TSUB=250); aliasing error ~e^-35, and the
// uniform 0.5x scale cancels exactly in maxnorm. 72.2 us.
//
// Round-7 theory: top-5 profile rows are all the harness's 256 MiB workspace
// re-poison fills (39.3 us @ 85% HBM peak) — a fixed floor. Our stroke kernel
// runs at 1 block/CU = 1 wave/SIMD: zero TLP, so LDS latency (~120cy
// single-outstanding) and exp chains are fully exposed, i.e. latency-bound,
// not throughput-bound (LDS traffic floor is only ~3 us).
// Round-7 change: split each stroke's t-range across TWO blocks (grid 512,
// 2 blocks/CU -> 2 waves/SIMD). Stroke blocks write RAW partial dot sums;
// the combine kernel (one block per batch image) adds the two halves, does
// the per-stroke max-reduce + tanh-norm, sums over K, final tanh-norm.
// Math identical up to f32 summation order (sum is linear; maxnorm identity
// max(acc*zp) == max(acc)*zp unchanged).
#define BSZ    64
#define KK     4
#define NPTS   5
#define RES    28
#define NSTEPS 500
#define TSUB   250              // sampled t-steps (stride 2 over 500)
#define THALF  125              // t-steps per stroke block (2 blocks/stroke)
#define NPIX   (RES * RES)      // 784
#define EPSV   1e-6f

// One block per (b,k,half): 512 blocks, 256 threads. Threads 0..195 own 4 px.
__global__ __launch_bounds__(256) void strokes_part_kernel(
    const float* __restrict__ z_what,
    const float* __restrict__ z_where,
    const float* __restrict__ sigma_p,
    float* __restrict__ ws)
{
    __shared__ float sCx[THALF];
    __shared__ float sCy[THALF];
    __shared__ __align__(16) float sEx[THALF * RES];   // Ex[t][x], row 112B
    __shared__ __align__(16) float sEy[THALF * RES];   // Ey[t][y]

    const int blk  = blockIdx.x;          // bk*2 + half
    const int bk   = blk >> 1;
    const int half = blk & 1;
    const int tid  = threadIdx.x;

    const float s   = z_where[bk * 3 + 0];
    const float shx = z_where[bk * 3 + 1];
    const float shy = z_where[bk * 3 + 2];

    float px[NPTS], py[NPTS];
#pragma unroll
    for (int p = 0; p < NPTS; ++p) {
        px[p] = z_what[(bk * NPTS + p) * 2 + 0] * s + shx;
        py[p] = z_what[(bk * NPTS + p) * 2 + 1] * s + shy;
    }

    // Bernstein basis (deg 4) at t = 2*(jbase+j)/499, dotted with ctrl pts.
    const int jbase = half * THALF;
    for (int j = tid; j < THALF; j += 256) {
        float tt = (float)(2 * (jbase + j)) * (1.0f / (float)(NSTEPS - 1));
        float u  = 1.0f - tt;
        float u2 = u * u, t2 = tt * tt;
        float c0 = u2 * u2;
        float c1 = 4.0f * tt * u2 * u;
        float c2 = 6.0f * t2 * u2;
        float c3 = 4.0f * t2 * tt * u;
        float c4 = t2 * t2;
        sCx[j] = c0 * px[0] + c1 * px[1] + c2 * px[2] + c3 * px[3] + c4 * px[4];
        sCy[j] = c0 * py[0] + c1 * py[1] + c2 * py[2] + c3 * py[3] + c4 * py[4];
    }
    __syncthreads();

    const float sigma = sigma_p[0];
    const float inv   = 1.0f / (2.0f * sigma * sigma);

    // Fill Ex[t][x] = exp(-(g(x)-cx(t))^2 inv), Ey likewise. 3500 slots.
    for (int i = tid; i < THALF * RES; i += 256) {
        int t = i / RES;
        int x = i - t * RES;
        float g   = (float)x * (1.0f / (float)(RES - 1));
        float dxx = g - sCx[t];
        float dyy = g - sCy[t];
        sEx[i] = __expf(-dxx * dxx * inv);
        sEy[i] = __expf(-dyy * dyy * inv);
    }
    __syncthreads();

    // Separable partial dot: acc[y][x] = sum_{t in half} Ey[t][y] * Ex[t][x].
    const bool own = (tid < 196);
    const int  y   = tid / 7;            // row (when own)
    const int  x0  = (tid % 7) * 4;      // 4 consecutive pixels per thread

    float acc[4] = {0.f, 0.f, 0.f, 0.f};
    if (own) {
        const float* ebase = sEx + x0;
        const float* ybase = sEy + y;
        for (int t = 0; t < THALF; ++t) {
            float  ey = ybase[t * RES];
            float4 ex = *(const float4*)(ebase + t * RES);  // 16B-aligned
            acc[0] += ey * ex.x;
            acc[1] += ey * ex.y;
            acc[2] += ey * ex.z;
            acc[3] += ey * ex.w;
        }
        float4 o = {acc[0], acc[1], acc[2], acc[3]};
        *(float4*)(ws + blk * NPIX + tid * 4) = o;          // raw partials
    }
}

// One block per batch image b: add the 2 halves per stroke, per-stroke
// max-reduce + tanh-norm, sum over K, final tanh_norm(slope), write f32 out.
__global__ __launch_bounds__(256) void combine_kernel(
    const float* __restrict__ z_pres,
    const float* __restrict__ ws,
    const float* __restrict__ slope_strk_p,
    const float* __restrict__ slope_p,
    float* __restrict__ out)
{
    __shared__ float sRed[4];
    const int b   = blockIdx.x;
    const int tid = threadIdx.x;
    const bool own = (tid < 196);

    const float sstrk = slope_strk_p[0];
    const float itnh  = 1.0f / tanhf(sstrk);

    float img[4] = {0.f, 0.f, 0.f, 0.f};

#pragma unroll
    for (int k = 0; k < KK; ++k) {
        const int bk = b * KK + k;
        float v[4] = {0.f, 0.f, 0.f, 0.f};
        if (own) {
            float4 a0 = *(const float4*)(ws + (bk * 2 + 0) * NPIX + tid * 4);
            float4 a1 = *(const float4*)(ws + (bk * 2 + 1) * NPIX + tid * 4);
            v[0] = a0.x + a1.x; v[1] = a0.y + a1.y;
            v[2] = a0.z + a1.z; v[3] = a0.w + a1.w;
        }
        // Block max-reduction (inactive threads hold 0; all values >= 0).
        float m = fmaxf(fmaxf(v[0], v[1]), fmaxf(v[2], v[3]));
        for (int off = 32; off > 0; off >>= 1)
            m = fmaxf(m, __shfl_down(m, off, 64));
        if ((tid & 63) == 0) sRed[tid >> 6] = m;
        __syncthreads();
        m = fmaxf(fmaxf(sRed[0], sRed[1]), fmaxf(sRed[2], sRed[3]));
        __syncthreads();   // sRed reused next k

        const float zp    = z_pres[bk];               // uniform[0,1) -> >= 0
        const float denom = 1.0f / (m * zp + EPSV);   // max(v*zp)==max(v)*zp
#pragma unroll
        for (int j = 0; j < 4; ++j)
            img[j] += tanhf(v[j] * zp * denom * sstrk) * itnh;
    }

    if (own) {
        const float sl   = slope_p[0];
        const float itsl = 1.0f / tanhf(sl);
        float4 o;
        o.x = tanhf(img[0] * sl) * itsl;
        o.y = tanhf(img[1] * sl) * itsl;
        o.z = tanhf(img[2] * sl) * itsl;
        o.w = tanhf(img[3] * sl) * itsl;
        *(float4*)(out + b * NPIX + tid * 4) = o;
    }
}

extern "C" void kernel_launch(void* const* d_in, const int* in_sizes, int n_in,
                              void* d_out, int out_size, void* d_ws, size_t ws_size,
                              hipStream_t stream) {
    const float* z_pres     = (const float*)d_in[0];
    const float* z_what     = (const float*)d_in[1];
    const float* z_where    = (const float*)d_in[2];
    const float* sigma      = (const float*)d_in[3];
    const float* slope_strk = (const float*)d_in[4];
    const float* slope      = (const float*)d_in[5];

    float* ws  = (float*)d_ws;          // 512*784 f32 = 1.6 MB scratch
    float* out = (float*)d_out;

    strokes_part_kernel<<<BSZ * KK * 2, 256, 0, stream>>>(z_what, z_where,
                                                          sigma, ws);
    combine_kernel<<<BSZ, 256, 0, stream>>>(z_pres, ws, slope_strk, slope, out);
}

// Round 2
// 71.390 us; speedup vs baseline: 1.0406x; 1.0406x over previous
//
#include <hip/hip_runtime.h>

// Problem: BS=64, K=4, PTS=5, RES=28, STEPS=500. All tensors f32.
// Output (64,1,28,28) f32.
//
// Round-5 lesson: fused flag-sync version REGRESSED — cross-block sync
// storms on CDNA4. Two-kernel structure retained.
// Round-6: t-subsampling stride 2 (TSUB=250); aliasing ~e^-35; 72.2 us.
// Round-7 FAILED (74.3): t-split across 2 blocks kept per-CU LDS-pipe
// cycles constant -> dot is LDS-THROUGHPUT-bound, not latency-bound.
//   per t-iter/wave: ds_read_b32(5.8cy) + ds_read_b128(12cy) on the one
//   LDS pipe/CU; 250x4 waves = ~17.8k cy = 7.4 us/CU. Round-6's -6 us for
//   halving TSUB confirms LDS cycles drive total.
// Round-8 change: register 4x4 outer-product tiling of the dot.
//   C[28][28] += Ey[t][:]^T Ex[t][:]  -> thread owns a 4x4 px tile, reads
//   4 ey + 4 ex as TWO ds_read_b128 per t (24 cy per 16 px vs 71 before,
//   3.7x fewer LDS-pipe cycles). 49 tiles x 5 t-chunks(50) = 245 threads.
//   Partials reduced via reused sEx region; round-0 epilogue + combine.
#define BSZ    64
#define KK     4
#define NPTS   5
#define RES    28
#define NSTEPS 500
#define TSUB   250              // sampled t-steps (stride 2 over 500)
#define TCH    50               // t-steps per chunk (5 chunks)
#define NPIX   (RES * RES)      // 784
#define EPSV   1e-6f

// One block per (b,k) stroke; 256 threads.
__global__ __launch_bounds__(256) void strokes_kernel(
    const float* __restrict__ z_pres,
    const float* __restrict__ z_what,
    const float* __restrict__ z_where,
    const float* __restrict__ sigma_p,
    const float* __restrict__ slope_strk_p,
    float* __restrict__ ws)
{
    __shared__ float sCx[TSUB];
    __shared__ float sCy[TSUB];
    __shared__ __align__(16) float sEx[TSUB * RES];   // Ex[t][x], row 112B
    __shared__ __align__(16) float sEy[TSUB * RES];   // Ey[t][y]
    __shared__ float sRed[4];

    const int bk  = blockIdx.x;   // b*K + k
    const int tid = threadIdx.x;

    const float s   = z_where[bk * 3 + 0];
    const float shx = z_where[bk * 3 + 1];
    const float shy = z_where[bk * 3 + 2];

    float px[NPTS], py[NPTS];
#pragma unroll
    for (int p = 0; p < NPTS; ++p) {
        px[p] = z_what[(bk * NPTS + p) * 2 + 0] * s + shx;
        py[p] = z_what[(bk * NPTS + p) * 2 + 1] * s + shy;
    }

    // Bernstein basis (deg 4) at t = (2j)/499, dotted with ctrl pts -> LDS.
    for (int j = tid; j < TSUB; j += 256) {
        float tt = (float)(2 * j) * (1.0f / (float)(NSTEPS - 1));
        float u  = 1.0f - tt;
        float u2 = u * u, t2 = tt * tt;
        float c0 = u2 * u2;
        float c1 = 4.0f * tt * u2 * u;
        float c2 = 6.0f * t2 * u2;
        float c3 = 4.0f * t2 * tt * u;
        float c4 = t2 * t2;
        sCx[j] = c0 * px[0] + c1 * px[1] + c2 * px[2] + c3 * px[3] + c4 * px[4];
        sCy[j] = c0 * py[0] + c1 * py[1] + c2 * py[2] + c3 * py[3] + c4 * py[4];
    }
    __syncthreads();

    const float sigma = sigma_p[0];
    const float inv   = 1.0f / (2.0f * sigma * sigma);

    // Fill Ex[t][x] = exp(-(g(x)-cx(t))^2 inv), Ey likewise. 7000 slots.
    for (int i = tid; i < TSUB * RES; i += 256) {
        int t = i / RES;
        int x = i - t * RES;
        float g   = (float)x * (1.0f / (float)(RES - 1));
        float dxx = g - sCx[t];
        float dyy = g - sCy[t];
        sEx[i] = __expf(-dxx * dxx * inv);
        sEy[i] = __expf(-dyy * dyy * inv);
    }
    __syncthreads();

    // 4x4 register-tiled outer-product dot, t split in 5 chunks of 50.
    // tile = tid % 49 -> (ty,tx) 4x4 px block; chunk = tid / 49.
    const int  tile  = tid % 49;
    const int  chunk = tid / 49;
    const bool act   = (tid < 245);
    const int  ty    = (tile / 7) * 4;
    const int  tx    = (tile % 7) * 4;

    float a0x=0.f,a0y=0.f,a0z=0.f,a0w=0.f;
    float a1x=0.f,a1y=0.f,a1z=0.f,a1w=0.f;
    float a2x=0.f,a2y=0.f,a2z=0.f,a2w=0.f;
    float a3x=0.f,a3y=0.f,a3z=0.f,a3w=0.f;
    if (act) {
        const float* exb = sEx + tx;
        const float* eyb = sEy + ty;
        const int t1 = chunk * TCH + TCH;
#pragma unroll 2
        for (int t = chunk * TCH; t < t1; ++t) {
            float4 ex = *(const float4*)(exb + t * RES);  // 16B-aligned
            float4 ey = *(const float4*)(eyb + t * RES);  // 16B-aligned
            a0x += ey.x * ex.x; a0y += ey.x * ex.y; a0z += ey.x * ex.z; a0w += ey.x * ex.w;
            a1x += ey.y * ex.x; a1y += ey.y * ex.y; a1z += ey.y * ex.z; a1w += ey.y * ex.w;
            a2x += ey.z * ex.x; a2y += ey.z * ex.y; a2z += ey.z * ex.z; a2w += ey.z * ex.w;
            a3x += ey.w * ex.x; a3y += ey.w * ex.y; a3z += ey.w * ex.z; a3w += ey.w * ex.w;
        }
    }
    __syncthreads();

    // Reduce the 5 t-chunks: partials into reused sEx region (3920 floats).
    float* pacc = sEx;
    if (act) {
        float4 r0 = {a0x, a0y, a0z, a0w};
        float4 r1 = {a1x, a1y, a1z, a1w};
        float4 r2 = {a2x, a2y, a2z, a2w};
        float4 r3 = {a3x, a3y, a3z, a3w};
        float* base = pacc + chunk * NPIX + ty * RES + tx;   // 16B-aligned
        *(float4*)(base + 0 * RES) = r0;
        *(float4*)(base + 1 * RES) = r1;
        *(float4*)(base + 2 * RES) = r2;
        *(float4*)(base + 3 * RES) = r3;
    }
    __syncthreads();

    // Per-pixel sum over chunks; threads 0..195 own 4 px of a row.
    const bool own = (tid < 196);
    const int  y   = tid / 7;
    const int  x0  = (tid % 7) * 4;
    float acc[4] = {0.f, 0.f, 0.f, 0.f};
    if (own) {
        const float* base = pacc + y * RES + x0;
#pragma unroll
        for (int c = 0; c < 5; ++c) {
            float4 v = *(const float4*)(base + c * NPIX);
            acc[0] += v.x; acc[1] += v.y; acc[2] += v.z; acc[3] += v.w;
        }
    }

    // Block max-reduction (inactive threads hold 0; all values >= 0).
    float m = 0.f;
#pragma unroll
    for (int sl = 0; sl < 4; ++sl) m = fmaxf(m, acc[sl]);
    for (int off = 32; off > 0; off >>= 1)
        m = fmaxf(m, __shfl_down(m, off, 64));
    if ((tid & 63) == 0) sRed[tid >> 6] = m;
    __syncthreads();
    m = fmaxf(fmaxf(sRed[0], sRed[1]), fmaxf(sRed[2], sRed[3]));

    const float zp    = z_pres[bk];               // uniform[0,1) -> >= 0
    const float denom = 1.0f / (m * zp + EPSV);   // max(acc*zp) == max(acc)*zp
    const float sstrk = slope_strk_p[0];
    const float itnh  = 1.0f / tanhf(sstrk);

    if (own) {
        float4 o;
        o.x = tanhf(acc[0] * zp * denom * sstrk) * itnh;
        o.y = tanhf(acc[1] * zp * denom * sstrk) * itnh;
        o.z = tanhf(acc[2] * zp * denom * sstrk) * itnh;
        o.w = tanhf(acc[3] * zp * denom * sstrk) * itnh;
        *(float4*)(ws + bk * NPIX + tid * 4) = o;
    }
}

// Sum over K strokes + final tanh_norm(slope), write f32 output (64,1,28,28).
__global__ __launch_bounds__(256) void combine_kernel(
    const float* __restrict__ ws,
    const float* __restrict__ slope_p,
    float* __restrict__ out)
{
    int idx = blockIdx.x * 256 + threadIdx.x;
    if (idx >= BSZ * NPIX) return;
    int b = idx / NPIX;
    int p = idx - b * NPIX;
    const float* base = ws + b * (KK * NPIX) + p;
    float sum = (base[0] + base[NPIX]) + (base[2 * NPIX] + base[3 * NPIX]);
    float sl  = slope_p[0];
    out[idx] = tanhf(sum * sl) / tanhf(sl);
}

extern "C" void kernel_launch(void* const* d_in, const int* in_sizes, int n_in,
                              void* d_out, int out_size, void* d_ws, size_t ws_size,
                              hipStream_t stream) {
    const float* z_pres     = (const float*)d_in[0];
    const float* z_what     = (const float*)d_in[1];
    const float* z_where    = (const float*)d_in[2];
    const float* sigma      = (const float*)d_in[3];
    const float* slope_strk = (const float*)d_in[4];
    const float* slope      = (const float*)d_in[5];

    float* ws  = (float*)d_ws;          // 256*784 f32 = 784 KB scratch
    float* out = (float*)d_out;

    strokes_kernel<<<BSZ * KK, 256, 0, stream>>>(z_pres, z_what, z_where,
                                                 sigma, slope_strk, ws);
    combine_kernel<<<(BSZ * NPIX + 255) / 256, 256, 0, stream>>>(ws, slope, out);
}